// Round 3
// baseline (60.706 us; speedup 1.0000x reference)
//
#include <hip/hip_runtime.h>
#include <stdint.h>

typedef __attribute__((ext_vector_type(8))) short bf16x8;
typedef __attribute__((ext_vector_type(4))) float f32x4;

#define NROWS 4096
#define DDIM  1024
#define NB    32        // 4096 / 128 panels
#define NBLK  528       // NB*(NB+1)/2 triangular tiles
#define COS_EPS 1e-8f

__device__ __forceinline__ ushort f2bf(float x) {
  union { float f; uint32_t u; } v; v.f = x;
  uint32_t r = (v.u + 0x7FFF + ((v.u >> 16) & 1)) >> 16;  // RNE
  return (ushort)r;
}

__device__ __forceinline__ void gload16(const ushort* g, ushort* l) {
  __builtin_amdgcn_global_load_lds(
      (const __attribute__((address_space(1))) uint32_t*)g,
      (__attribute__((address_space(3))) uint32_t*)l, 16, 0, 0);
}

// ---------------- prep: sq, 1/norm, bf16 copy ----------------
extern "C" __global__ void __launch_bounds__(256) prep_kernel(
    const float* __restrict__ F, ushort* __restrict__ Fb,
    float* __restrict__ sq, float* __restrict__ rn) {
  const int row  = blockIdx.x * 4 + (threadIdx.x >> 6);
  const int lane = threadIdx.x & 63;
  const float4* src = (const float4*)(F + (size_t)row * DDIM);
  ushort4* dst = (ushort4*)(Fb + (size_t)row * DDIM);
  float s = 0.f;
#pragma unroll
  for (int it = 0; it < 4; ++it) {
    float4 v = src[it * 64 + lane];
    s += v.x * v.x + v.y * v.y + v.z * v.z + v.w * v.w;
    ushort4 b;
    b.x = f2bf(v.x); b.y = f2bf(v.y); b.z = f2bf(v.z); b.w = f2bf(v.w);
    dst[it * 64 + lane] = b;
  }
#pragma unroll
  for (int off = 32; off; off >>= 1) s += __shfl_down(s, off);
  if (lane == 0) {
    sq[row] = s;
    rn[row] = 1.0f / fmaxf(sqrtf(s), COS_EPS);
  }
}

// ---------------- fused gram (bf16 MFMA) + loss epilogue ----------------
// 128x128 tile, BK=32, 4 LDS buffers, 3-deep counted-vmcnt prefetch,
// (row>>1)&3 chunk swizzle, super-tiled + XCD-chunked block decode.
extern "C" __global__ void __launch_bounds__(256) gram_kernel(
    const ushort* __restrict__ Fb, const float* __restrict__ sq,
    const float* __restrict__ rn, const int* __restrict__ y,
    float* __restrict__ partials) {
  // per buffer: 128 rows x 32 bf16 = 8 KB; 4 bufs x (A+B) = 64 KB
  __shared__ __align__(16) ushort As[4][4096];
  __shared__ __align__(16) ushort Bs[4][4096];

  // ---- XCD-chunked swizzle (528 = 8 * 66, bijective) + super-tile decode ----
  int s = (int)(blockIdx.x & 7) * 66 + (int)(blockIdx.x >> 3);
  int bi, bj;
  {
    int rem = s, SI = 0, SJ = 0;
    bool found = false;
    for (SI = 0; SI < 8 && !found; ++SI) {
      for (SJ = SI; SJ < 8; ++SJ) {
        int cnt = (SI == SJ) ? 10 : 16;
        if (rem < cnt) { found = true; break; }
        rem -= cnt;
      }
      if (found) break;
    }
    int li, lj;
    if (SI == SJ) {            // 4x4 triangular super: 10 tiles
      li = 0;
      while (rem >= 4 - li) { rem -= 4 - li; ++li; }
      lj = li + rem;
    } else {                   // full 4x4 super: 16 tiles
      li = rem >> 2; lj = rem & 3;
    }
    bi = SI * 4 + li; bj = SJ * 4 + lj;
  }

  const int tid  = threadIdx.x;
  const int lane = tid & 63;
  const int wid  = tid >> 6;
  const int wrow = wid >> 1;   // 2x2 wave grid, each wave 64x64 out
  const int wcol = wid & 1;

  f32x4 acc[4][4] = {};

  // ---- staging: thread (wid,lane) stages 2 chunks each for A and B ----
  // chunk c = p*256 + wid*64 + lane  ->  row = p*64 + wid*16 + (lane>>2),
  // slot col = lane&3. Source col chunk = (lane&3) ^ f(row), f(row)=(row>>1)&3
  // = (lane>>3)&3 here. LDS stays linear (global_load_lds requirement).
  const int srow = wid * 16 + (lane >> 2);
  const int scol = ((lane & 3) ^ ((lane >> 3) & 3)) * 8;
  const ushort* gA0 = Fb + (size_t)(bi * 128 + srow) * DDIM + scol;
  const ushort* gA1 = gA0 + (size_t)64 * DDIM;
  const ushort* gB0 = Fb + (size_t)(bj * 128 + srow) * DDIM + scol;
  const ushort* gB1 = gB0 + (size_t)64 * DDIM;
  const int lslot0 = wid * 512 + lane * 8;   // ushort units
  const int lslot1 = 2048 + lslot0;

  // ---- fragment read offsets (swizzled): LDS[row][cc] = G[row][cc^f(row)] ----
  const int fr = lane & 15, fg = lane >> 4;
  const int fswz = (fg ^ ((fr >> 1) & 3)) * 8;
  int aoff[4], boff[4];
#pragma unroll
  for (int m = 0; m < 4; ++m) {
    aoff[m] = (wrow * 64 + m * 16 + fr) * 32 + fswz;
    boff[m] = (wcol * 64 + m * 16 + fr) * 32 + fswz;
  }

#define STAGE(kt) do {                                                      \
    const int _c = (kt) * 32;                                               \
    ushort* _a = &As[(kt) & 3][0];                                          \
    ushort* _b = &Bs[(kt) & 3][0];                                          \
    gload16(gA0 + _c, _a + lslot0);                                         \
    gload16(gA1 + _c, _a + lslot1);                                         \
    gload16(gB0 + _c, _b + lslot0);                                         \
    gload16(gB1 + _c, _b + lslot1);                                         \
  } while (0)

#define COMPUTE(kt) do {                                                    \
    const ushort* _a = &As[(kt) & 3][0];                                    \
    const ushort* _b = &Bs[(kt) & 3][0];                                    \
    bf16x8 _av[4], _bv[4];                                                  \
    _Pragma("unroll")                                                       \
    for (int _m = 0; _m < 4; ++_m) {                                        \
      _av[_m] = *(const bf16x8*)(_a + aoff[_m]);                            \
      _bv[_m] = *(const bf16x8*)(_b + boff[_m]);                            \
    }                                                                       \
    _Pragma("unroll")                                                       \
    for (int _m = 0; _m < 4; ++_m)                                          \
      _Pragma("unroll")                                                     \
      for (int _n = 0; _n < 4; ++_n)                                        \
        acc[_m][_n] = __builtin_amdgcn_mfma_f32_16x16x32_bf16(              \
            _av[_m], _bv[_n], acc[_m][_n], 0, 0, 0);                        \
  } while (0)

  // prologue: 3 tiles in flight (12 loads/wave)
  STAGE(0); STAGE(1); STAGE(2);

#pragma unroll 1
  for (int kt = 0; kt < 32; ++kt) {
    // counted vmcnt: wait only for the oldest tile; keep 2 in flight
    if (kt < 30)       asm volatile("s_waitcnt vmcnt(8)" ::: "memory");
    else if (kt == 30) asm volatile("s_waitcnt vmcnt(4)" ::: "memory");
    else               asm volatile("s_waitcnt vmcnt(0)" ::: "memory");
    __builtin_amdgcn_s_barrier();
    asm volatile("" ::: "memory");   // fence: no ds_read hoists above barrier
    if (kt < 29) STAGE(kt + 3);      // overwrites buf read at iter kt-1 (done)
    COMPUTE(kt);
  }

#undef STAGE
#undef COMPUTE

  // ---------- epilogue ----------
  const int rbase = bi * 128 + wrow * 64;
  const int cbase = bj * 128 + wcol * 64;
  const float w = (bi == bj) ? 1.0f : 2.0f;

  float sqr[16], rnr[16];
  int   yr[16];
#pragma unroll
  for (int m = 0; m < 4; ++m)
#pragma unroll
    for (int v = 0; v < 4; ++v) {
      int gi = rbase + m * 16 + (lane >> 4) * 4 + v;
      sqr[m * 4 + v] = sq[gi];
      rnr[m * 4 + v] = rn[gi];
      yr[m * 4 + v]  = y[gi];
    }
  float sqc[4], rnc[4];
  int   yc[4];
#pragma unroll
  for (int n = 0; n < 4; ++n) {
    int gj = cbase + n * 16 + (lane & 15);
    sqc[n] = sq[gj];
    rnc[n] = rn[gj];
    yc[n]  = y[gj];
  }

  float lsum = 0.f;
#pragma unroll
  for (int m = 0; m < 4; ++m)
#pragma unroll
    for (int n = 0; n < 4; ++n)
#pragma unroll
      for (int v = 0; v < 4; ++v) {
        float g  = acc[m][n][v];
        float d2 = sqr[m * 4 + v] + sqc[n] - 2.0f * g;
        float dist = d2 > 0.f ? sqrtf(d2) : 0.f;
        float sim  = g * rnr[m * 4 + v] * rnc[n];
        float sgn  = (yr[m * 4 + v] == yc[n]) ? 1.0f : -1.0f;
        lsum += sgn * (dist - sim);
      }
  lsum *= w;

#pragma unroll
  for (int off = 32; off; off >>= 1) lsum += __shfl_down(lsum, off);
  __shared__ float wsum[4];
  if (lane == 0) wsum[wid] = lsum;
  __syncthreads();
  if (tid == 0) partials[blockIdx.x] = wsum[0] + wsum[1] + wsum[2] + wsum[3];
}

// ---------------- deterministic final reduce ----------------
extern "C" __global__ void __launch_bounds__(256) reduce_kernel(
    const float* __restrict__ partials, float* __restrict__ out) {
  float s = 0.f;
  for (int i = threadIdx.x; i < NBLK; i += 256) s += partials[i];
#pragma unroll
  for (int off = 32; off; off >>= 1) s += __shfl_down(s, off);
  __shared__ float ws[4];
  if ((threadIdx.x & 63) == 0) ws[threadIdx.x >> 6] = s;
  __syncthreads();
  if (threadIdx.x == 0) out[0] = ws[0] + ws[1] + ws[2] + ws[3];
}

extern "C" void kernel_launch(void* const* d_in, const int* in_sizes, int n_in,
                              void* d_out, int out_size, void* d_ws, size_t ws_size,
                              hipStream_t stream) {
  const float* F = (const float*)d_in[0];
  const int*   y = (const int*)d_in[1];
  float* out = (float*)d_out;

  ushort* Fb = (ushort*)d_ws;                                 // 8 MB bf16
  float*  sq = (float*)((char*)d_ws + (size_t)NROWS * DDIM * 2);
  float*  rn = sq + NROWS;
  float*  partials = rn + NROWS;

  prep_kernel<<<NROWS / 4, 256, 0, stream>>>(F, Fb, sq, rn);
  gram_kernel<<<NBLK, 256, 0, stream>>>(Fb, sq, rn, y, partials);
  reduce_kernel<<<1, 256, 0, stream>>>(partials, out);
}